// Round 6
// baseline (402.006 us; speedup 1.0000x reference)
//
#include <hip/hip_runtime.h>
#include <math.h>

#define T_TOK 16384
#define DIM   2048
#define NE    64
#define NACT  8
#define ALPHA 1e-4f
#define EPSV  1e-9f
#define TAU   2.5e-4f

typedef __attribute__((ext_vector_type(8))) short bf16x8;
typedef __attribute__((ext_vector_type(4))) float f32x4;

// RNE float->bf16 (values finite/small; no nan handling needed)
__device__ inline unsigned short bf16_rne(float f) {
    unsigned b = __float_as_uint(f);
    unsigned r = b + 0x7FFFu + ((b >> 16) & 1u);
    return (unsigned short)(r >> 16);
}

// Split 8 floats into hi (bf16 truncation) + lo (bf16 RNE of residual).
// x ~= xh+xl to ~2^-17 relative: 3-term MFMA logit sigma ~1.5e-5 << TAU.
__device__ inline void split8(const float4 a0, const float4 a1,
                              bf16x8& h, bf16x8& l) {
    float f[8] = {a0.x, a0.y, a0.z, a0.w, a1.x, a1.y, a1.z, a1.w};
#pragma unroll
    for (int i = 0; i < 8; ++i) {
        unsigned b  = __float_as_uint(f[i]);
        unsigned hb = b & 0xFFFF0000u;
        h[i] = (short)(hb >> 16);
        l[i] = (short)bf16_rne(f[i] - __uint_as_float(hb));
    }
}

// ---------------------------------------------------------------------------
// prep: W hi/lo split + zero logit accumulator + zero scalars.
// Grid 4096 x 256 = exactly T_TOK*NE threads.
// ---------------------------------------------------------------------------
__global__ __launch_bounds__(256) void prep_k(const float* __restrict__ W,
                                              unsigned short* __restrict__ Wh,
                                              unsigned short* __restrict__ Wl,
                                              float* __restrict__ Aout,
                                              float* __restrict__ gz) {
    const int i = blockIdx.x * 256 + threadIdx.x;
    if (i < NE * DIM) {
        const float f = W[i];
        const unsigned b  = __float_as_uint(f);
        const unsigned hb = b & 0xFFFF0000u;
        Wh[i] = (unsigned short)(hb >> 16);
        Wl[i] = bf16_rne(f - __uint_as_float(hb));
    }
    Aout[i] = 0.0f;
    if (i < 130) gz[i] = 0.0f;   // gP[64], gC[64], cntp, done
}

// ---------------------------------------------------------------------------
// GEMM pass: logit partials via bf16x3 MFMA, fragments direct from global.
// Grid 2048 = 1024 token-groups x 2 K-halves; waves K-split the 1024-k half
// into 256-k slices (8 K-steps). 8 blocks/CU -> 32 waves/CU (R5 was 16 and
// still latency-bound at 36% occupancy). LDS-combine the 4 wave partials,
// then fp32 atomicAdd into the zeroed Aout logit array (2 adders/address).
// MFMA 16x16x32 bf16 layouts (m89/m120-verified).
// ---------------------------------------------------------------------------
__global__ __launch_bounds__(256, 6) void gemm_k(
        const float* __restrict__ x,
        const unsigned short* __restrict__ Wh,
        const unsigned short* __restrict__ Wl,
        float* __restrict__ Aout) {
    __shared__ __align__(16) float comb[4 * 16 * 68];   // 17408 B

    const int tid  = threadIdx.x;
    const int wv   = tid >> 6;
    const int lane = tid & 63;
    const int c15  = lane & 15;
    const int q    = lane >> 4;
    const int tg   = blockIdx.x >> 1;
    const int kh   = blockIdx.x & 1;
    const int tokBase = tg * 16;
    const int kb   = kh * 1024 + wv * 256;

    const float* xp = x + (size_t)(tokBase + c15) * DIM + kb + q * 8;
    const unsigned short* whp[4];
    const unsigned short* wlp[4];
#pragma unroll
    for (int j = 0; j < 4; ++j) {
        whp[j] = Wh + (size_t)(16 * j + c15) * DIM + kb + q * 8;
        wlp[j] = Wl + (size_t)(16 * j + c15) * DIM + kb + q * 8;
    }

    f32x4 acc[4];
#pragma unroll
    for (int j = 0; j < 4; ++j) acc[j] = (f32x4){0.f, 0.f, 0.f, 0.f};

    float4 ra[2][2];
    bf16x8 rh[2][4], rl[2][4];

#define LOADSTEP(s, c) {                                                  \
        const float* xpc = xp + 32 * (c);                                 \
        ra[s][0] = *(const float4*)xpc;                                   \
        ra[s][1] = *(const float4*)(xpc + 4);                             \
        _Pragma("unroll")                                                 \
        for (int j = 0; j < 4; ++j) {                                     \
            rh[s][j] = *(const bf16x8*)(whp[j] + 32 * (c));               \
            rl[s][j] = *(const bf16x8*)(wlp[j] + 32 * (c));               \
        }                                                                 \
    }

#define COMPSTEP(s) {                                                     \
        bf16x8 ah, al;                                                    \
        split8(ra[s][0], ra[s][1], ah, al);                               \
        _Pragma("unroll")                                                 \
        for (int j = 0; j < 4; ++j) {                                     \
            acc[j] = __builtin_amdgcn_mfma_f32_16x16x32_bf16(ah, rh[s][j], acc[j], 0, 0, 0); \
            acc[j] = __builtin_amdgcn_mfma_f32_16x16x32_bf16(ah, rl[s][j], acc[j], 0, 0, 0); \
            acc[j] = __builtin_amdgcn_mfma_f32_16x16x32_bf16(al, rh[s][j], acc[j], 0, 0, 0); \
        }                                                                 \
    }

    LOADSTEP(0, 0);
    LOADSTEP(1, 1);
#pragma unroll
    for (int c = 0; c < 8; c += 2) {
        COMPSTEP(0);
        if (c + 2 < 8) LOADSTEP(0, c + 2);
        COMPSTEP(1);
        if (c + 3 < 8) LOADSTEP(1, c + 3);
    }
#undef LOADSTEP
#undef COMPSTEP

    // write K-partials (C-layout) to LDS
#pragma unroll
    for (int j = 0; j < 4; ++j)
#pragma unroll
        for (int r = 0; r < 4; ++r)
            comb[wv * 1088 + (q * 4 + r) * 68 + 16 * j + c15] = acc[j][r];
    __syncthreads();

    // combine 4 wave-partials, atomically add the half into Aout
    {
        const int t  = tid >> 4;
        const int e0 = (tid & 15) * 4;
        const float4 s0 = *(const float4*)&comb[0 * 1088 + t * 68 + e0];
        const float4 s1 = *(const float4*)&comb[1 * 1088 + t * 68 + e0];
        const float4 s2 = *(const float4*)&comb[2 * 1088 + t * 68 + e0];
        const float4 s3 = *(const float4*)&comb[3 * 1088 + t * 68 + e0];
        float* dst = Aout + (size_t)(tokBase + t) * NE + e0;
        atomicAdd(dst + 0, s0.x + s1.x + s2.x + s3.x);
        atomicAdd(dst + 1, s0.y + s1.y + s2.y + s3.y);
        atomicAdd(dst + 2, s0.z + s1.z + s2.z + s3.z);
        atomicAdd(dst + 3, s0.w + s1.w + s2.w + s3.w);
    }
}

// ---------------------------------------------------------------------------
// Gate pass: sigmoid(logits) -> top-8 + gate normalization + near-tie
// marking + loss partials. Grid 1024 x 256 (16 tokens/block, 4/wave).
// ---------------------------------------------------------------------------
__global__ __launch_bounds__(256) void gate_k(
        const float* __restrict__ Aout,
        const float* __restrict__ bias,
        float* __restrict__ gates,
        float* __restrict__ idxf,
        float* __restrict__ gP,
        float* __restrict__ gC,
        int*   __restrict__ cntp,
        int*   __restrict__ list) {
    __shared__ __align__(16) float aff[16 * 68];
    __shared__ float Pl[NE];
    __shared__ float Cl[NE];

    const int tid  = threadIdx.x;
    const int wv   = tid >> 6;
    const int lane = tid & 63;
    const int tokBase = blockIdx.x * 16;

    if (tid < NE) { Pl[tid] = 0.0f; Cl[tid] = 0.0f; }

    {
        const int t  = tid >> 4;
        const int e0 = (tid & 15) * 4;
        const float4 lg = *(const float4*)(Aout + (size_t)(tokBase + t) * NE + e0);
        float4 af;
        af.x = 1.0f / (1.0f + expf(-lg.x));
        af.y = 1.0f / (1.0f + expf(-lg.y));
        af.z = 1.0f / (1.0f + expf(-lg.z));
        af.w = 1.0f / (1.0f + expf(-lg.w));
        *(float4*)&aff[t * 68 + e0] = af;
    }
    __syncthreads();

    const float b = bias[lane];
    float pacc = 0.0f;
    float cacc = 0.0f;

    for (int it = 0; it < 4; ++it) {
        const int tl = wv * 4 + it;
        const int gt = tokBase + tl;
        const float a = aff[tl * 68 + lane];

        float rs = a;
#pragma unroll
        for (int off = 32; off; off >>= 1) rs += __shfl_xor(rs, off, 64);
        pacc += a / (rs + EPSV);

        float s = a + b;
        float gk[NACT];
        int   ik[NACT];
        float gsum = 0.0f;
        float prevv = 0.0f, gmin = 1e30f;
        int   selcnt = 0;

#pragma unroll
        for (int k = 0; k < 9; ++k) {
            float v = s;
            int  vi = lane;
#pragma unroll
            for (int off = 32; off; off >>= 1) {
                const float ov = __shfl_xor(v, off, 64);
                const int   oi = __shfl_xor(vi, off, 64);
                if (ov > v || (ov == v && oi < vi)) { v = ov; vi = oi; }
            }
            if (k > 0) gmin = fminf(gmin, prevv - v);
            prevv = v;
            if (k < 8) {
                const float ga = __shfl(a, vi, 64);
                gk[k] = ga; ik[k] = vi; gsum += ga;
                if (lane == vi) { s = -INFINITY; selcnt++; }
            }
        }

        const bool marked = (gmin < TAU);
        if (!marked) cacc += (float)selcnt;

        if (lane == 0) {
            const float inv = 1.0f / (gsum + EPSV);
#pragma unroll
            for (int k = 0; k < NACT; ++k) {
                gates[(size_t)gt * NACT + k] = gk[k] * inv;
                idxf [(size_t)gt * NACT + k] = (float)ik[k];
            }
            if (marked) {
                const int slot = atomicAdd(cntp, 1);
                list[slot] = gt;
            }
        }
    }

    atomicAdd(&Pl[lane], pacc);
    atomicAdd(&Cl[lane], cacc);
    __syncthreads();
    if (tid < NE) {
        atomicAdd(&gP[tid], Pl[tid]);
        atomicAdd(&gC[tid], Cl[tid]);
    }
}

// ---------------------------------------------------------------------------
// Fixup + loss: fp64 recompute of near-tie chain candidates for marked
// tokens (grid-strided, 256 one-wave blocks), then last-done block computes
// the balance loss (device-scope ticket).
// ---------------------------------------------------------------------------
__global__ __launch_bounds__(64) void fix_k(
        const float* __restrict__ x,
        const float* __restrict__ Wg,
        const float* __restrict__ bias,
        const float* __restrict__ Aout,
        float* __restrict__ gates,
        float* __restrict__ idxf,
        const float* __restrict__ gP,
        float* __restrict__ gC,
        const int* __restrict__ cntp,
        int*   __restrict__ done,
        const int* __restrict__ list,
        float* __restrict__ lossOut) {
    const int lane = threadIdx.x;
    const int cnt = *cntp;
    float cacc = 0.0f;

    for (int idx = blockIdx.x; idx < cnt; idx += gridDim.x) {
        const int t = list[idx];
        const float lg  = Aout[(size_t)t * NE + lane];
        const float a32 = 1.0f / (1.0f + expf(-lg));   // same expr as gate_k
        const float bl  = bias[lane];
        const float s32 = a32 + bl;

        // hoist x row: k = 4*lane + 256*m
        const float* xr = x + (size_t)t * DIM;
        float4 xv[8];
#pragma unroll
        for (int m = 0; m < 8; ++m) xv[m] = *(const float4*)(xr + 4 * lane + 256 * m);

        // fp32 scan of top-16
        float vr[16];
        int   ir[16];
        float ss = s32;
#pragma unroll
        for (int k = 0; k < 16; ++k) {
            float v = ss;
            int  vi = lane;
#pragma unroll
            for (int off = 32; off; off >>= 1) {
                const float ov = __shfl_xor(v, off, 64);
                const int   oi = __shfl_xor(vi, off, 64);
                if (ov > v || (ov == v && oi < vi)) { v = ov; vi = oi; }
            }
            vr[k] = v; ir[k] = vi;
            if (lane == vi) ss = -INFINITY;
        }

        // chain closure: components of adjacent gap < TAU touching ranks 0..8
        bool needs[16];
#pragma unroll
        for (int k = 0; k < 16; ++k) needs[k] = false;
#pragma unroll
        for (int k = 1; k <= 8; ++k)
            if (vr[k - 1] - vr[k] < TAU) { needs[k - 1] = true; needs[k] = true; }
#pragma unroll
        for (int k = 9; k < 16; ++k)
            if (needs[k - 1] && (vr[k - 1] - vr[k] < TAU)) needs[k] = true;

        unsigned long long mb = 0ull;
#pragma unroll
        for (int k = 0; k < 16; ++k)
            if (needs[k]) mb |= (1ull << ir[k]);

        // fp64 recompute of candidates, two at a time
        double ad = (double)a32;
        while (mb) {
            const int e0 = __ffsll(mb) - 1;
            mb &= mb - 1;
            int e1 = -1;
            if (mb) { e1 = __ffsll(mb) - 1; mb &= mb - 1; }
            const float* wr0 = Wg + (size_t)e0 * DIM;
            const float* wr1 = Wg + (size_t)((e1 >= 0) ? e1 : e0) * DIM;
            float4 w0[8], w1[8];
#pragma unroll
            for (int m = 0; m < 8; ++m) {
                w0[m] = *(const float4*)(wr0 + 4 * lane + 256 * m);
                w1[m] = *(const float4*)(wr1 + 4 * lane + 256 * m);
            }
            double z0 = 0.0, z1 = 0.0;
#pragma unroll
            for (int m = 0; m < 8; ++m) {
                z0 = fma((double)xv[m].x, (double)w0[m].x, z0);
                z0 = fma((double)xv[m].y, (double)w0[m].y, z0);
                z0 = fma((double)xv[m].z, (double)w0[m].z, z0);
                z0 = fma((double)xv[m].w, (double)w0[m].w, z0);
                z1 = fma((double)xv[m].x, (double)w1[m].x, z1);
                z1 = fma((double)xv[m].y, (double)w1[m].y, z1);
                z1 = fma((double)xv[m].z, (double)w1[m].z, z1);
                z1 = fma((double)xv[m].w, (double)w1[m].w, z1);
            }
#pragma unroll
            for (int off = 32; off; off >>= 1) {
                z0 += __shfl_xor(z0, off, 64);
                z1 += __shfl_xor(z1, off, 64);
            }
            const double af0 = 1.0 / (1.0 + exp(-z0));
            if (lane == e0) ad = af0;
            if (e1 >= 0) {
                const double af1 = 1.0 / (1.0 + exp(-z1));
                if (lane == e1) ad = af1;
            }
        }

        // final fp64 top-8 (fp64 candidates, fp32-promoted others)
        double sd = ad + (double)bl;
        double gk[NACT];
        int    ik[NACT];
        double gsum = 0.0;
#pragma unroll
        for (int k = 0; k < NACT; ++k) {
            double v = sd;
            int   vi = lane;
#pragma unroll
            for (int off = 32; off; off >>= 1) {
                const double ov = __shfl_xor(v, off, 64);
                const int    oi = __shfl_xor(vi, off, 64);
                if (ov > v || (ov == v && oi < vi)) { v = ov; vi = oi; }
            }
            const double ga = __shfl(ad, vi, 64);
            gk[k] = ga; ik[k] = vi; gsum += ga;
            if (lane == vi) { sd = -INFINITY; cacc += 1.0f; }
        }

        if (lane == 0) {
            const double inv = 1.0 / (gsum + (double)EPSV);
#pragma unroll
            for (int k = 0; k < NACT; ++k) {
                gates[(size_t)t * NACT + k] = (float)(gk[k] * inv);
                idxf [(size_t)t * NACT + k] = (float)ik[k];
            }
        }
    }

    atomicAdd(&gC[lane], cacc);
    __threadfence();
    int tk = 0;
    if (lane == 0) tk = atomicAdd(done, 1);
    tk = __shfl(tk, 0, 64);
    if (tk == (int)gridDim.x - 1) {
        __threadfence();
        const float f = gC[lane] * ((float)NE / (float)(NACT * T_TOK));
        const float P = gP[lane] / (float)T_TOK;
        float v = f * P;
#pragma unroll
        for (int off = 32; off; off >>= 1) v += __shfl_xor(v, off, 64);
        if (lane == 0) lossOut[0] = ALPHA * v;
    }
}

extern "C" void kernel_launch(void* const* d_in, const int* in_sizes, int n_in,
                              void* d_out, int out_size, void* d_ws, size_t ws_size,
                              hipStream_t stream) {
    const float* x    = (const float*)d_in[0];
    const float* Wg   = (const float*)d_in[1];
    const float* bias = (const float*)d_in[2];
    float* out = (float*)d_out;
    float* gates = out;
    float* idxf  = out + (size_t)T_TOK * NACT;
    float* loss  = out + 2 * (size_t)T_TOK * NACT;

    unsigned short* Wh = (unsigned short*)d_ws;            // 256 KB
    unsigned short* Wl = Wh + (size_t)NE * DIM;            // 256 KB
    float* Aout = (float*)(Wl + (size_t)NE * DIM);         // 4 MB (logits)
    float* gP   = Aout + (size_t)T_TOK * NE;               // 64
    float* gC   = gP + NE;                                 // 64
    int*   cntp = (int*)(gC + NE);                         // 1
    int*   done = cntp + 1;                                // 1
    int*   list = done + 1;                                // 16384

    prep_k<<<(T_TOK * NE) / 256, 256, 0, stream>>>(Wg, Wh, Wl, Aout, gP);
    gemm_k<<<2048, 256, 0, stream>>>(x, Wh, Wl, Aout);
    gate_k<<<T_TOK / 16, 256, 0, stream>>>(Aout, bias, gates, idxf,
                                           gP, gC, cntp, list);
    fix_k<<<256, 64, 0, stream>>>(x, Wg, bias, Aout, gates, idxf,
                                  gP, gC, cntp, done, list, loss);
}

// Round 7
// 327.583 us; speedup vs baseline: 1.2272x; 1.2272x over previous
//
#include <hip/hip_runtime.h>
#include <math.h>

#define T_TOK 16384
#define DIM   2048
#define NE    64
#define NACT  8
#define ALPHA 1e-4f
#define EPSV  1e-9f
#define TAU   2.5e-4f

#define WPITCH 520   // shorts per W row in LDS: 1040 B (16B-mult), 4-dword bank stride -> uniform 8/bank on b128

typedef __attribute__((ext_vector_type(8))) short bf16x8;
typedef __attribute__((ext_vector_type(4))) float f32x4;

// RNE float->bf16 (values finite/small; no nan handling needed)
__device__ inline unsigned short bf16_rne(float f) {
    unsigned b = __float_as_uint(f);
    unsigned r = b + 0x7FFFu + ((b >> 16) & 1u);
    return (unsigned short)(r >> 16);
}

// ---------------------------------------------------------------------------
// zero: logit accumulator (4 MB) + scalars.
// ---------------------------------------------------------------------------
__global__ __launch_bounds__(256) void zero_k(float* __restrict__ Aout,
                                              float* __restrict__ gz) {
    const int i = blockIdx.x * 256 + threadIdx.x;   // 262144 float4s
    ((float4*)Aout)[i] = (float4){0.f, 0.f, 0.f, 0.f};
    if (blockIdx.x == 0 && threadIdx.x < 130) gz[threadIdx.x] = 0.0f;
}

// ---------------------------------------------------------------------------
// GEMM: logit partials via bf16x3 MFMA. W k-slice (64e x 512k, bf16 hi+lo)
// staged+converted into LDS once per block (130 KB); K-loop is barrier-free:
// x via 2 direct gathers/step, W via ds_read_b128. This cuts scattered
// global loads 5x vs R6 (655k -> 131k) — R5/R6 showed duration tracks that
// count (~100cyc each) regardless of occupancy.
// Grid 256 = 64 token-groups x 4 k-slices; block 1024 thr (16 waves), each
// wave 16 tok x 64 exp x 512 k. fp32 atomicAdd combine (4 adders/logit).
// MFMA 16x16x32 bf16 layouts (m89/m120-verified).
// ---------------------------------------------------------------------------
__global__ __launch_bounds__(1024) void gemm_k(
        const float* __restrict__ x,
        const float* __restrict__ W,
        float* __restrict__ Aout) {
    __shared__ __align__(16) unsigned short Whs[NE * WPITCH];
    __shared__ __align__(16) unsigned short Wls[NE * WPITCH];

    const int tid = threadIdx.x;
    const int kq  = blockIdx.x & 3;
    const int tg  = blockIdx.x >> 2;
    const int tokBase = tg * 256;
    const int kb  = kq * 512;

    // ---- stage + convert W slice: thread (e=tid>>4, c=tid&15) does 32 k ----
    {
        const int e = tid >> 4;
        const int c = tid & 15;
        const float* wr = W + (size_t)e * DIM + kb + c * 32;
        unsigned short* dh = &Whs[e * WPITCH + c * 32];
        unsigned short* dl = &Wls[e * WPITCH + c * 32];
#pragma unroll
        for (int m = 0; m < 8; ++m) {
            const float4 v = *(const float4*)(wr + m * 4);
            const float f[4] = {v.x, v.y, v.z, v.w};
            unsigned short hp[4], lp[4];
#pragma unroll
            for (int u = 0; u < 4; ++u) {
                const unsigned bb = __float_as_uint(f[u]);
                const unsigned hb = bb & 0xFFFF0000u;
                hp[u] = (unsigned short)(hb >> 16);
                lp[u] = bf16_rne(f[u] - __uint_as_float(hb));
            }
            *(ushort4*)(dh + m * 4) = *(const ushort4*)hp;
            *(ushort4*)(dl + m * 4) = *(const ushort4*)lp;
        }
    }
    __syncthreads();

    const int wv   = tid >> 6;
    const int lane = tid & 63;
    const int c15  = lane & 15;
    const int q    = lane >> 4;

    const float* xp = x + (size_t)(tokBase + wv * 16 + c15) * DIM + kb + q * 8;
    const unsigned short* whB = &Whs[c15 * WPITCH + q * 8];
    const unsigned short* wlB = &Wls[c15 * WPITCH + q * 8];

    f32x4 acc[4];
#pragma unroll
    for (int j = 0; j < 4; ++j) acc[j] = (f32x4){0.f, 0.f, 0.f, 0.f};

    float4 ra[2][2];
    bf16x8 rh[2][4], rl[2][4];

#define LOADSTEP(s, st) {                                                 \
        const float* xpc = xp + 32 * (st);                                \
        ra[s][0] = *(const float4*)xpc;                                   \
        ra[s][1] = *(const float4*)(xpc + 4);                             \
        _Pragma("unroll")                                                 \
        for (int j = 0; j < 4; ++j) {                                     \
            rh[s][j] = *(const bf16x8*)(whB + j * 16 * WPITCH + (st) * 32); \
            rl[s][j] = *(const bf16x8*)(wlB + j * 16 * WPITCH + (st) * 32); \
        }                                                                 \
    }

#define COMPSTEP(s) {                                                     \
        bf16x8 ah, al;                                                    \
        {                                                                 \
            float f[8] = {ra[s][0].x, ra[s][0].y, ra[s][0].z, ra[s][0].w, \
                          ra[s][1].x, ra[s][1].y, ra[s][1].z, ra[s][1].w};\
            _Pragma("unroll")                                             \
            for (int i = 0; i < 8; ++i) {                                 \
                const unsigned bb = __float_as_uint(f[i]);                \
                const unsigned hb = bb & 0xFFFF0000u;                     \
                ah[i] = (short)(hb >> 16);                                \
                al[i] = (short)bf16_rne(f[i] - __uint_as_float(hb));      \
            }                                                             \
        }                                                                 \
        _Pragma("unroll")                                                 \
        for (int j = 0; j < 4; ++j) {                                     \
            acc[j] = __builtin_amdgcn_mfma_f32_16x16x32_bf16(ah, rh[s][j], acc[j], 0, 0, 0); \
            acc[j] = __builtin_amdgcn_mfma_f32_16x16x32_bf16(ah, rl[s][j], acc[j], 0, 0, 0); \
            acc[j] = __builtin_amdgcn_mfma_f32_16x16x32_bf16(al, rh[s][j], acc[j], 0, 0, 0); \
        }                                                                 \
    }

    LOADSTEP(0, 0);
    LOADSTEP(1, 1);
#pragma unroll
    for (int c = 0; c < 16; c += 2) {
        COMPSTEP(0);
        if (c + 2 < 16) LOADSTEP(0, c + 2);
        COMPSTEP(1);
        if (c + 3 < 16) LOADSTEP(1, c + 3);
    }
#undef LOADSTEP
#undef COMPSTEP

    // ---- epilogue: atomic combine (C: row=q*4+r token, col=16j+c15 expert)
    const int trow = tokBase + wv * 16 + q * 4;
#pragma unroll
    for (int j = 0; j < 4; ++j)
#pragma unroll
        for (int r = 0; r < 4; ++r)
            atomicAdd(&Aout[(size_t)(trow + r) * NE + 16 * j + c15], acc[j][r]);
}

// ---------------------------------------------------------------------------
// Gate: sigmoid(logits) -> rank-based top-8 (rank = #{j: s_j>s_e or tie with
// lower idx} == exact lax.top_k order), gate normalization, near-tie
// marking, loss partials. Grid 1024 x 256 (16 tok/block, 4/wave).
// ---------------------------------------------------------------------------
__global__ __launch_bounds__(256) void gate_k(
        const float* __restrict__ Aout,
        const float* __restrict__ bias,
        float* __restrict__ gates,
        float* __restrict__ idxf,
        float* __restrict__ gP,
        float* __restrict__ gC,
        int*   __restrict__ cntp,
        int*   __restrict__ list) {
    __shared__ __align__(16) float aff[16 * 68];
    __shared__ __align__(16) float sS[4][64];   // scores by lane
    __shared__ __align__(16) float bS[4][64];   // scores by rank
    __shared__ __align__(16) float bA[4][64];   // affinity by rank
    __shared__ float Pl[NE];
    __shared__ float Cl[NE];

    const int tid  = threadIdx.x;
    const int wv   = tid >> 6;
    const int lane = tid & 63;
    const int tokBase = blockIdx.x * 16;

    if (tid < NE) { Pl[tid] = 0.0f; Cl[tid] = 0.0f; }

    {
        const int t  = tid >> 4;
        const int e0 = (tid & 15) * 4;
        const float4 lg = *(const float4*)(Aout + (size_t)(tokBase + t) * NE + e0);
        float4 af;
        af.x = 1.0f / (1.0f + expf(-lg.x));
        af.y = 1.0f / (1.0f + expf(-lg.y));
        af.z = 1.0f / (1.0f + expf(-lg.z));
        af.w = 1.0f / (1.0f + expf(-lg.w));
        *(float4*)&aff[t * 68 + e0] = af;
    }
    __syncthreads();

    const float b = bias[lane];
    float pacc = 0.0f;
    float cacc = 0.0f;

    for (int it = 0; it < 4; ++it) {
        const int tl = wv * 4 + it;
        const int gt = tokBase + tl;
        const float a = aff[tl * 68 + lane];

        float rs = a;
#pragma unroll
        for (int off = 32; off; off >>= 1) rs += __shfl_xor(rs, off, 64);
        pacc += a / (rs + EPSV);

        const float s = a + b;
        sS[wv][lane] = s;
        __syncthreads();

        int rank = 0;
#pragma unroll
        for (int j4 = 0; j4 < 16; ++j4) {
            const float4 sv = *(const float4*)&sS[wv][j4 * 4];
            rank += (sv.x > s || (sv.x == s && (j4 * 4 + 0) < lane));
            rank += (sv.y > s || (sv.y == s && (j4 * 4 + 1) < lane));
            rank += (sv.z > s || (sv.z == s && (j4 * 4 + 2) < lane));
            rank += (sv.w > s || (sv.w == s && (j4 * 4 + 3) < lane));
        }
        bS[wv][rank] = s;
        bA[wv][rank] = a;
        __syncthreads();

        // marking: min adjacent gap among sorted ranks 0..8
        const float4 p0 = *(const float4*)&bS[wv][0];
        const float4 p1 = *(const float4*)&bS[wv][4];
        const float v8v = bS[wv][8];
        float gmin = p0.x - p0.y;
        gmin = fminf(gmin, p0.y - p0.z);
        gmin = fminf(gmin, p0.z - p0.w);
        gmin = fminf(gmin, p0.w - p1.x);
        gmin = fminf(gmin, p1.x - p1.y);
        gmin = fminf(gmin, p1.y - p1.z);
        gmin = fminf(gmin, p1.z - p1.w);
        gmin = fminf(gmin, p1.w - v8v);
        const bool marked = (gmin < TAU);

        const float4 a0 = *(const float4*)&bA[wv][0];
        const float4 a1 = *(const float4*)&bA[wv][4];
        const float gsum = ((((((a0.x + a0.y) + a0.z) + a0.w) + a1.x) + a1.y) + a1.z) + a1.w;
        const float inv = 1.0f / (gsum + EPSV);

        if (rank < NACT) {
            gates[(size_t)gt * NACT + rank] = a * inv;
            idxf [(size_t)gt * NACT + rank] = (float)lane;
            if (!marked) cacc += 1.0f;
        }
        if (lane == 0 && marked) {
            const int slot = atomicAdd(cntp, 1);
            list[slot] = gt;
        }
        __syncthreads();
    }

    atomicAdd(&Pl[lane], pacc);
    atomicAdd(&Cl[lane], cacc);
    __syncthreads();
    if (tid < NE) {
        atomicAdd(&gP[tid], Pl[tid]);
        atomicAdd(&gC[tid], Cl[tid]);
    }
}

// ---------------------------------------------------------------------------
// Fixup + loss: fp64 recompute of near-tie chain candidates (grid-strided,
// 2048 one-wave blocks — R6's 256 starved it), rank-based selection, then
// last-done block computes the balance loss.
// ---------------------------------------------------------------------------
__global__ __launch_bounds__(64) void fix_k(
        const float* __restrict__ x,
        const float* __restrict__ Wg,
        const float* __restrict__ bias,
        const float* __restrict__ Aout,
        float* __restrict__ gates,
        float* __restrict__ idxf,
        const float* __restrict__ gP,
        float* __restrict__ gC,
        const int* __restrict__ cntp,
        int*   __restrict__ done,
        const int* __restrict__ list,
        float* __restrict__ lossOut) {
    __shared__ __align__(16) float  sS[64];
    __shared__ __align__(16) float  bS[64];
    __shared__ __align__(16) int    bI[64];
    __shared__ __align__(16) double dS[64];
    __shared__ __align__(16) double dR[64];

    const int lane = threadIdx.x;
    const int cnt = *cntp;
    float cacc = 0.0f;

    for (int idx = blockIdx.x; idx < cnt; idx += gridDim.x) {
        const int t = list[idx];
        const float lg  = Aout[(size_t)t * NE + lane];
        const float a32 = 1.0f / (1.0f + expf(-lg));   // same expr as gate_k
        const float bl  = bias[lane];
        const float s32 = a32 + bl;

        // hoist x row: k = 4*lane + 256*m
        const float* xr = x + (size_t)t * DIM;
        float4 xv[8];
#pragma unroll
        for (int m = 0; m < 8; ++m) xv[m] = *(const float4*)(xr + 4 * lane + 256 * m);

        sS[lane] = s32;
        __syncthreads();
        int rank = 0;
#pragma unroll
        for (int j4 = 0; j4 < 16; ++j4) {
            const float4 sv = *(const float4*)&sS[j4 * 4];
            rank += (sv.x > s32 || (sv.x == s32 && (j4 * 4 + 0) < lane));
            rank += (sv.y > s32 || (sv.y == s32 && (j4 * 4 + 1) < lane));
            rank += (sv.z > s32 || (sv.z == s32 && (j4 * 4 + 2) < lane));
            rank += (sv.w > s32 || (sv.w == s32 && (j4 * 4 + 3) < lane));
        }
        bS[rank] = s32;
        bI[rank] = lane;
        __syncthreads();

        // sorted top-16 + chain closure touching ranks 0..8
        float vr[16];
        int   ir[16];
#pragma unroll
        for (int k4 = 0; k4 < 4; ++k4) {
            const float4 vv = *(const float4*)&bS[k4 * 4];
            const int4   ii = *(const int4*)&bI[k4 * 4];
            vr[k4 * 4 + 0] = vv.x; vr[k4 * 4 + 1] = vv.y;
            vr[k4 * 4 + 2] = vv.z; vr[k4 * 4 + 3] = vv.w;
            ir[k4 * 4 + 0] = ii.x; ir[k4 * 4 + 1] = ii.y;
            ir[k4 * 4 + 2] = ii.z; ir[k4 * 4 + 3] = ii.w;
        }
        bool needs[16];
#pragma unroll
        for (int k = 0; k < 16; ++k) needs[k] = false;
#pragma unroll
        for (int k = 1; k <= 8; ++k)
            if (vr[k - 1] - vr[k] < TAU) { needs[k - 1] = true; needs[k] = true; }
#pragma unroll
        for (int k = 9; k < 16; ++k)
            if (needs[k - 1] && (vr[k - 1] - vr[k] < TAU)) needs[k] = true;

        unsigned long long mb = 0ull;
#pragma unroll
        for (int k = 0; k < 16; ++k)
            if (needs[k]) mb |= (1ull << ir[k]);

        // fp64 recompute of candidates, two at a time
        double ad = (double)a32;
        while (mb) {
            const int e0 = __ffsll(mb) - 1;
            mb &= mb - 1;
            int e1 = -1;
            if (mb) { e1 = __ffsll(mb) - 1; mb &= mb - 1; }
            const float* wr0 = Wg + (size_t)e0 * DIM;
            const float* wr1 = Wg + (size_t)((e1 >= 0) ? e1 : e0) * DIM;
            float4 w0[8], w1[8];
#pragma unroll
            for (int m = 0; m < 8; ++m) {
                w0[m] = *(const float4*)(wr0 + 4 * lane + 256 * m);
                w1[m] = *(const float4*)(wr1 + 4 * lane + 256 * m);
            }
            double z0 = 0.0, z1 = 0.0;
#pragma unroll
            for (int m = 0; m < 8; ++m) {
                z0 = fma((double)xv[m].x, (double)w0[m].x, z0);
                z0 = fma((double)xv[m].y, (double)w0[m].y, z0);
                z0 = fma((double)xv[m].z, (double)w0[m].z, z0);
                z0 = fma((double)xv[m].w, (double)w0[m].w, z0);
                z1 = fma((double)xv[m].x, (double)w1[m].x, z1);
                z1 = fma((double)xv[m].y, (double)w1[m].y, z1);
                z1 = fma((double)xv[m].z, (double)w1[m].z, z1);
                z1 = fma((double)xv[m].w, (double)w1[m].w, z1);
            }
#pragma unroll
            for (int off = 32; off; off >>= 1) {
                z0 += __shfl_xor(z0, off, 64);
                z1 += __shfl_xor(z1, off, 64);
            }
            const double af0 = 1.0 / (1.0 + exp(-z0));
            if (lane == e0) ad = af0;
            if (e1 >= 0) {
                const double af1 = 1.0 / (1.0 + exp(-z1));
                if (lane == e1) ad = af1;
            }
        }

        // final fp64 rank-based top-8
        const double sd = ad + (double)bl;
        dS[lane] = sd;
        __syncthreads();
        int r2 = 0;
#pragma unroll
        for (int j2 = 0; j2 < 32; ++j2) {
            const double2 dv = *(const double2*)&dS[j2 * 2];
            r2 += (dv.x > sd || (dv.x == sd && (2 * j2 + 0) < lane));
            r2 += (dv.y > sd || (dv.y == sd && (2 * j2 + 1) < lane));
        }
        dR[r2] = ad;
        __syncthreads();
        const double2 g0 = *(const double2*)&dR[0];
        const double2 g1 = *(const double2*)&dR[2];
        const double2 g2 = *(const double2*)&dR[4];
        const double2 g3 = *(const double2*)&dR[6];
        const double gsum = ((((((g0.x + g0.y) + g1.x) + g1.y) + g2.x) + g2.y) + g3.x) + g3.y;
        const double inv = 1.0 / (gsum + (double)EPSV);

        if (r2 < NACT) {
            gates[(size_t)t * NACT + r2] = (float)(ad * inv);
            idxf [(size_t)t * NACT + r2] = (float)lane;
            cacc += 1.0f;
        }
        __syncthreads();
    }

    atomicAdd(&gC[lane], cacc);
    __threadfence();
    int tk = 0;
    if (lane == 0) tk = atomicAdd(done, 1);
    tk = __shfl(tk, 0, 64);
    if (tk == (int)gridDim.x - 1) {
        __threadfence();
        const float f = gC[lane] * ((float)NE / (float)(NACT * T_TOK));
        const float P = gP[lane] / (float)T_TOK;
        float v = f * P;
#pragma unroll
        for (int off = 32; off; off >>= 1) v += __shfl_xor(v, off, 64);
        if (lane == 0) lossOut[0] = ALPHA * v;
    }
}

extern "C" void kernel_launch(void* const* d_in, const int* in_sizes, int n_in,
                              void* d_out, int out_size, void* d_ws, size_t ws_size,
                              hipStream_t stream) {
    const float* x    = (const float*)d_in[0];
    const float* Wg   = (const float*)d_in[1];
    const float* bias = (const float*)d_in[2];
    float* out = (float*)d_out;
    float* gates = out;
    float* idxf  = out + (size_t)T_TOK * NACT;
    float* loss  = out + 2 * (size_t)T_TOK * NACT;

    float* Aout = (float*)d_ws;                   // 4 MB logits
    float* gP   = Aout + (size_t)T_TOK * NE;      // 64
    float* gC   = gP + NE;                        // 64
    int*   cntp = (int*)(gC + NE);                // 1
    int*   done = cntp + 1;                       // 1
    int*   list = done + 1;                       // 16384

    zero_k<<<1024, 256, 0, stream>>>(Aout, gP);
    gemm_k<<<256, 1024, 0, stream>>>(x, Wg, Aout);
    gate_k<<<T_TOK / 16, 256, 0, stream>>>(Aout, bias, gates, idxf,
                                           gP, gC, cntp, list);
    fix_k<<<2048, 64, 0, stream>>>(x, Wg, bias, Aout, gates, idxf,
                                   gP, gC, cntp, done, list, loss);
}